// Round 9
// baseline (194.295 us; speedup 1.0000x reference)
//
#include <hip/hip_runtime.h>
#include <math.h>

// Problem constants (B=1, S=8, N=M=768, D=64, IT=16, RATIO=0.6, THR=0.75, K=8)
#define NN 768
#define MM 768
#define DD 64
#define BI 8            // B*S
#define RN 460          // int(0.6*768)
#define KTOP 8

// Output layout (concatenated flat: ti, tm, topk_err), all f32
static constexpr size_t OFF_TI = 0;                                  // (1,8,768,768)
static constexpr size_t OFF_TM = (size_t)KTOP * NN * MM;             // (1,8,64,64)
static constexpr size_t OFF_TE = OFF_TM + (size_t)KTOP * DD * DD;    // (1,8)

// Workspace layout. No zero-init: every location written before read.
static constexpr size_t NUMP_OFF  = 0;                                     // numpart (64,8,64,64)
static constexpr size_t MODEL_OFF = NUMP_OFF + (size_t)64 * BI * DD * DD;  // model (8,64,64)
static constexpr size_t XT_OFF    = MODEL_OFF + (size_t)BI * DD * DD;      // xt (8,768,64)
static constexpr size_t ERR_OFF   = XT_OFF + (size_t)BI * NN * DD;         // err (8,768,768)
static constexpr size_t FEND      = ERR_OFF + (size_t)BI * NN * MM;
static constexpr size_t ESUM_B = FEND * 4;            // float[1152]
static constexpr size_t ECNT_B = ESUM_B + 1152 * 4;   // int[1152]
static constexpr size_t DENP_B = ECNT_B + 1152 * 4;   // int[512]
static constexpr size_t PM_B   = DENP_B + 512 * 4 + 32;  // u64[8*768*12] packed mask (8-aligned)

__device__ __forceinline__ unsigned f2key(float f) {
  unsigned u = __float_as_uint(f);
  return (u & 0x80000000u) ? ~u : (u | 0x80000000u);
}
__device__ __forceinline__ float key2f(unsigned k) {
  unsigned u = (k & 0x80000000u) ? (k ^ 0x80000000u) : ~k;
  return __uint_as_float(u);
}

// 4 consecutive mask elems (qm&km) -> 4-bit nibble. e is elem index, e%4==0.
__device__ __forceinline__ unsigned pack4(const void* qm, const void* km, int flag, size_t e) {
  if (flag) {
    uint4 qa = *(const uint4*)((const unsigned*)qm + e);
    uint4 ka = *(const uint4*)((const unsigned*)km + e);
    return ((qa.x && ka.x) ? 1u : 0u) | ((qa.y && ka.y) ? 2u : 0u) |
           ((qa.z && ka.z) ? 4u : 0u) | ((qa.w && ka.w) ? 8u : 0u);
  } else {
    unsigned qa = *(const unsigned*)((const unsigned char*)qm + e);
    unsigned ka = *(const unsigned*)((const unsigned char*)km + e);
    return (((qa & 0xFFu) && (ka & 0xFFu)) ? 1u : 0u) |
           (((qa & 0xFF00u) && (ka & 0xFF00u)) ? 2u : 0u) |
           (((qa & 0xFF0000u) && (ka & 0xFF0000u)) ? 4u : 0u) |
           (((qa & 0xFF000000u) && (ka & 0xFF000000u)) ? 8u : 0u);
  }
}

// 16 nibbles (one per byte of uint4) -> u64 word
__device__ __forceinline__ unsigned long long asm16(uint4 q4) {
  unsigned dw[4] = {q4.x, q4.y, q4.z, q4.w};
  unsigned long long w = 0;
#pragma unroll
  for (int q = 0; q < 4; q++) {
    w |= (unsigned long long)(dw[q] & 0xFu) << (16 * q + 0);
    w |= (unsigned long long)((dw[q] >> 8) & 0xFu) << (16 * q + 4);
    w |= (unsigned long long)((dw[q] >> 16) & 0xFu) << (16 * q + 8);
    w |= (unsigned long long)((dw[q] >> 24) & 0xFu) << (16 * q + 12);
  }
  return w;
}

// Kernel 1 (pack + masked t-GEMM + num-partial fused). Block (ntile,c,b):
//  A) packs its own 64x64 mask tile (chain-free nibble->LDS->word) + 80 remainder
//     words so pmw covers all (768 rows x 12 words) per b; stores raw words to pmw.
//  B) masked col-sum GEMM: t[nl,e] = sum_{m in word c} bit * y[b,m,e] (3 VALU/MAC).
//  C) num partial: numpart[blin,b,d,e] = sum_{nl<64} x[n0+nl,d] * t[nl,e]
//     (num = x^T t is linear in the c-split, so partials sum later in k_model).
// tpart never touches memory. Mask reads overlap the VALU GEMMs.
__global__ __launch_bounds__(256) void k_solve(
    const float* __restrict__ qk, const float* __restrict__ kks,
    const void* __restrict__ qm, const void* __restrict__ km,
    float* __restrict__ numpart, int* __restrict__ denp,
    unsigned long long* __restrict__ pmw) {
  __shared__ float ys[64 * 68];            // union: y tile (B), then t tile (C)
  __shared__ float xs[64 * 68];            // x tile for (C)
  __shared__ unsigned char nib[1024];
  __shared__ unsigned char nib2[1280];
  __shared__ unsigned long long words[64];
  __shared__ int cntsh[4];
  __shared__ int flg[4];
  const int tid = threadIdx.x, lane = tid & 63, g = tid >> 6;
  const int ntile = blockIdx.x, c = blockIdx.y, b = blockIdx.z;
  const int n0 = ntile * 64, m0 = c * 64;
  const int blin = c * 8 + ntile;          // 0..63 per b

  // mask storage-layout detection (first 1 KB of qm, L2-hot): int32 0/1 data has
  // all-zero high bytes; bool-byte data has nonzero bytes at %4 != 0.
  {
    unsigned w0 = ((const unsigned*)qm)[tid];
    unsigned long long any = __ballot((w0 & 0xFFFFFF00u) != 0);
    if (lane == 0) flg[g] = (any != 0) ? 1 : 0;
  }
  __syncthreads();
  const int flag = (flg[0] | flg[1] | flg[2] | flg[3]) ? 0 : 1;   // 1 => int32 layout

  // (A) pack loads — all independent
  unsigned nbA[4];
#pragma unroll
  for (int k = 0; k < 4; k++) {
    int gi = tid + 256 * k;                // tile elem group [4gi,4gi+4)
    int r = gi >> 4, cc = (gi & 15) * 4;
    size_t e = ((size_t)b * NN + n0 + r) * MM + m0 + cc;
    nbA[k] = pack4(qm, km, flag, e);
  }
  unsigned nbB[5];
#pragma unroll
  for (int k = 0; k < 5; k++) {
    int t = tid + 256 * k;                 // 0..1279: 80 words x 16 groups
    int wi = t >> 4, q4i = t & 15;
    int W = blin * 80 + wi;                // 0..5119 remainder word id
    int n, w;
    if (W < 3072) { n = 512 + W / 12; w = W % 12; }
    else          { int r = W - 3072; n = r >> 2; w = 8 + (r & 3); }
    size_t e = ((size_t)b * NN + n) * MM + (size_t)w * 64 + q4i * 4;
    nbB[k] = pack4(qm, km, flag, e);
  }
  // stage y tile and x tile (independent of pack)
  for (int q = tid; q < 1024; q += 256) {
    int r = q >> 4, col = (q & 15) * 4;
    *(float4*)&ys[r * 68 + col] = *(const float4*)&kks[((size_t)b * MM + m0 + r) * DD + col];
    *(float4*)&xs[r * 68 + col] = *(const float4*)&qk[(size_t)(n0 + r) * DD + col];
  }
#pragma unroll
  for (int k = 0; k < 4; k++) nib[tid + 256 * k] = (unsigned char)nbA[k];
#pragma unroll
  for (int k = 0; k < 5; k++) nib2[tid + 256 * k] = (unsigned char)nbB[k];
  __syncthreads();
  // assemble words; store RAW to pmw (err/quant need full-range bits)
  if (tid < 64) {
    unsigned long long w = asm16(*(const uint4*)&nib[tid * 16]);
    words[tid] = w;
    pmw[((size_t)b * NN + n0 + tid) * 12 + c] = w;
  } else if (tid >= 128 && tid < 208) {
    int wi = tid - 128;
    unsigned long long w = asm16(*(const uint4*)&nib2[wi * 16]);
    int W = blin * 80 + wi;
    int n, ww;
    if (W < 3072) { n = 512 + W / 12; ww = W % 12; }
    else          { int r = W - 3072; n = r >> 2; ww = 8 + (r & 3); }
    pmw[((size_t)b * NN + n) * 12 + ww] = w;
  }
  __syncthreads();

  // (B) masked GEMM from words (wave-uniform LDS broadcast reads)
  unsigned wlo[16], whi[16];
  int cnt = 0;
#pragma unroll
  for (int i = 0; i < 16; i++) {
    int nl = g * 16 + i;
    unsigned long long w = words[nl];
    if (c == 7) w &= 0xFFFULL;             // solver samples m < 460 (448 + 12)
    wlo[i] = (unsigned)w; whi[i] = (unsigned)(w >> 32);
    if (n0 + nl < RN) cnt += __builtin_popcountll(w);
  }
  float acc[16];
#pragma unroll
  for (int i = 0; i < 16; i++) acc[i] = 0.f;
#pragma unroll 4
  for (int m = 0; m < 32; m++) {
    int yi = __float_as_int(ys[m * 68 + lane]);
#pragma unroll
    for (int i = 0; i < 16; i++) {
      int sel = ((int)(wlo[i] << (31 - m))) >> 31;
      acc[i] += __int_as_float(yi & sel);
    }
  }
#pragma unroll 4
  for (int m = 0; m < 32; m++) {
    int yi = __float_as_int(ys[(m + 32) * 68 + lane]);
#pragma unroll
    for (int i = 0; i < 16; i++) {
      int sel = ((int)(whi[i] << (31 - m))) >> 31;
      acc[i] += __int_as_float(yi & sel);
    }
  }
  if (lane == 0) cntsh[g] = cnt;           // cnt uniform across lanes
  __syncthreads();                         // all ys reads done -> safe to overwrite
  if (tid == 0) denp[blin * 8 + b] = cntsh[0] + cntsh[1] + cntsh[2] + cntsh[3];

  // (C) t into ys region (rows >= RN zeroed), then num partial GEMM
  float* tl = ys;
#pragma unroll
  for (int i = 0; i < 16; i++) {
    int nl = g * 16 + i;
    tl[nl * 68 + lane] = (n0 + nl < RN) ? acc[i] : 0.f;
  }
  __syncthreads();
  float acc2[16];
#pragma unroll
  for (int i = 0; i < 16; i++) acc2[i] = 0.f;
#pragma unroll 4
  for (int n = 0; n < 64; n++) {
    float tv = tl[n * 68 + lane];
#pragma unroll
    for (int i = 0; i < 16; i++) acc2[i] += xs[n * 68 + (g + 4 * i)] * tv;
  }
  float* np = numpart + ((size_t)blin * BI + b) * (DD * DD);
#pragma unroll
  for (int i = 0; i < 16; i++) np[(size_t)(g + 4 * i) * DD + lane] = acc2[i];
}

// Kernel 2: model[b] = (sum_{blin<64} numpart[blin,b]) / (den[b] + 1e-6)
__global__ __launch_bounds__(256) void k_model(
    const float* __restrict__ numpart, const int* __restrict__ denp, float* __restrict__ model) {
  __shared__ float invp;
  const int tid = threadIdx.x;
  const int b = blockIdx.x >> 3, part = blockIdx.x & 7;
  if (tid < 64) {
    int v = denp[tid * 8 + b];
#pragma unroll
    for (int o = 32; o > 0; o >>= 1) v += __shfl_xor(v, o);
    if (tid == 0) invp = 1.f / ((float)v + 1e-6f);
  }
  __syncthreads();
  float inv = invp;
  for (int l = part * 512 + tid; l < part * 512 + 512; l += 256) {
    float s = 0.f;
#pragma unroll
    for (int bl = 0; bl < 64; bl++) s += numpart[((size_t)bl * BI + b) * (DD * DD) + l];
    model[(size_t)b * (DD * DD) + l] = s * inv;
  }
}

// Kernel 3: xt[b,n,e] = sum_d x[n,d]*model[b,d,e]  (24 rows per block)
__global__ __launch_bounds__(256) void k_xt(
    const float* __restrict__ qk, const float* __restrict__ model, float* __restrict__ xt) {
  __shared__ float ml[DD * DD];
  const int tid = threadIdx.x, lane = tid & 63, g = tid >> 6;
  const int seg = blockIdx.x, b = blockIdx.y;
  const float4* msrc = (const float4*)(model + (size_t)b * DD * DD);
  for (int q = tid; q < 1024; q += 256) ((float4*)ml)[q] = msrc[q];
  __syncthreads();
#pragma unroll
  for (int rr = 0; rr < 6; rr++) {
    int n = seg * 24 + g * 6 + rr;
    float acc = 0.f;
#pragma unroll 8
    for (int d = 0; d < DD; d++) acc += qk[(size_t)n * DD + d] * ml[d * DD + lane];
    xt[((size_t)b * NN + n) * DD + lane] = acc;
  }
}

// Kernel 4: err[b,i,j] = ||xt_i||^2 + ||y_j||^2 - 2 xt_i.y_j, stored ONLY where mask
// bit set (quant gets validity from pm, so no INF sentinel writes).
__global__ __launch_bounds__(256) void k_err(
    const float* __restrict__ xt, const float* __restrict__ kks,
    const unsigned long long* __restrict__ pmw,
    float* __restrict__ err, float* __restrict__ esum, int* __restrict__ ecnt) {
  __shared__ float As[64 * 68];
  __shared__ float Bs[64 * 68];
  __shared__ float xx[64], yy[64];
  __shared__ float rsum[256];
  __shared__ int rcnt[256];
  const int b = blockIdx.z, wj = blockIdx.x;
  const int i0 = blockIdx.y * 64, j0 = wj * 64;
  const int tid = threadIdx.x, tx = tid & 15, ty = tid >> 4;
  const float* xb = xt + ((size_t)b * NN + i0) * DD;
  const float* yb = kks + ((size_t)b * MM + j0) * DD;
  for (int q = tid; q < 1024; q += 256) {
    int r = q >> 4, c = q & 15;
    *(float4*)&As[r * 68 + c * 4] = ((const float4*)(xb + (size_t)r * DD))[c];
    *(float4*)&Bs[r * 68 + c * 4] = ((const float4*)(yb + (size_t)r * DD))[c];
  }
  __syncthreads();
  if (tid < 64) {
    float s = 0.f;
#pragma unroll 8
    for (int k2 = 0; k2 < 64; k2++) { float v = As[tid * 68 + k2]; s += v * v; }
    xx[tid] = s;
  } else if (tid < 128) {
    int r = tid - 64;
    float s = 0.f;
#pragma unroll 8
    for (int k2 = 0; k2 < 64; k2++) { float v = Bs[r * 68 + k2]; s += v * v; }
    yy[r] = s;
  }
  __syncthreads();
  float acc[4][4];
#pragma unroll
  for (int ii = 0; ii < 4; ii++)
#pragma unroll
    for (int jj = 0; jj < 4; jj++) acc[ii][jj] = 0.f;
  for (int k2 = 0; k2 < 64; k2 += 4) {
    float4 av[4], bv[4];
#pragma unroll
    for (int ii = 0; ii < 4; ii++) av[ii] = *(const float4*)&As[(ty + 16 * ii) * 68 + k2];
#pragma unroll
    for (int jj = 0; jj < 4; jj++) bv[jj] = *(const float4*)&Bs[(tx + 16 * jj) * 68 + k2];
#pragma unroll
    for (int ii = 0; ii < 4; ii++)
#pragma unroll
      for (int jj = 0; jj < 4; jj++)
        acc[ii][jj] += av[ii].x * bv[jj].x + av[ii].y * bv[jj].y +
                       av[ii].z * bv[jj].z + av[ii].w * bv[jj].w;
  }
  float psum = 0.f;
  int pcnt = 0;
#pragma unroll
  for (int ii = 0; ii < 4; ii++) {
    int i = i0 + ty + 16 * ii;
    unsigned long long word = pmw[((size_t)b * NN + i) * 12 + wj];
    size_t rowb = ((size_t)b * NN + i) * MM;
#pragma unroll
    for (int jj = 0; jj < 4; jj++) {
      int j = j0 + tx + 16 * jj;
      int cm = (int)((word >> (tx + 16 * jj)) & 1ULL);
      float v = xx[ty + 16 * ii] + yy[tx + 16 * jj] - 2.f * acc[ii][jj];
      if (cm) { err[rowb + j] = v; psum += v; pcnt++; }
    }
  }
  rsum[tid] = psum;
  rcnt[tid] = pcnt;
  __syncthreads();
  for (int s = 128; s > 0; s >>= 1) {
    if (tid < s) { rsum[tid] += rsum[tid + s]; rcnt[tid] += rcnt[tid + s]; }
    __syncthreads();
  }
  if (tid == 0) {
    int t = b * 144 + blockIdx.y * 12 + wj;
    esum[t] = rsum[0];
    ecnt[t] = rcnt[0];
  }
}

// Kernel 5 (quant + rank fused): every block reduces the esum/ecnt partials (cheap,
// parallel), computes the descending order (== lax.top_k, K=S); block 0 writes TE+TM.
// Then per-row 0.75 nanquantile via ballot binary search (validity from pm bits).
__global__ __launch_bounds__(256) void k_quant(
    const float* __restrict__ err, const unsigned long long* __restrict__ pmw,
    const float* __restrict__ esum, const int* __restrict__ ecnt,
    const float* __restrict__ model, float* __restrict__ out) {
  __shared__ float avg_sh[BI];
  __shared__ int ords_sh[BI];
  const int bid = blockIdx.x, tid = threadIdx.x, lane = tid & 63, g = tid >> 6;
  const float INF = __builtin_inff();
  for (int h = 0; h < 2; h++) {
    int b = g * 2 + h, base = b * 144;
    float s = esum[base + lane] + esum[base + 64 + lane] + ((lane < 16) ? esum[base + 128 + lane] : 0.f);
    int ct = ecnt[base + lane] + ecnt[base + 64 + lane] + ((lane < 16) ? ecnt[base + 128 + lane] : 0);
#pragma unroll
    for (int o = 32; o > 0; o >>= 1) { s += __shfl_xor(s, o); ct += __shfl_xor(ct, o); }
    if (lane == 0) avg_sh[b] = s / (float)ct;
  }
  __syncthreads();
  if (tid == 0) {
    unsigned used = 0;
#pragma unroll
    for (int k = 0; k < KTOP; k++) {
      int best = 0;
      float bv = -INF;
#pragma unroll
      for (int b = 0; b < BI; b++)
        if (!((used >> b) & 1u) && avg_sh[b] > bv) { bv = avg_sh[b]; best = b; }
      used |= 1u << best;
      ords_sh[k] = best;
    }
  }
  __syncthreads();
  if (bid == 0) {
    if (tid < KTOP) out[OFF_TE + tid] = avg_sh[ords_sh[tid]];
    for (int l = tid; l < KTOP * DD * DD; l += 256) {
      int k = l >> 12;
      out[OFF_TM + l] = model[(size_t)ords_sh[k] * (DD * DD) + (l & (DD * DD - 1))];
    }
  }
  const int kk = bid >> 6, seg = bid & 63;
  const int b = ords_sh[kk];
  for (int rr = 0; rr < 3; rr++) {
    int n = seg * 12 + g * 3 + rr;
    const float* row = err + ((size_t)b * NN + n) * MM;
    size_t prow = ((size_t)b * NN + n) * 12;
    unsigned long long wd[3];
#pragma unroll
    for (int w = 0; w < 3; w++) wd[w] = pmw[prow + w * 4 + (lane >> 4)];
    int cp = (lane < 12) ? __builtin_popcountll(pmw[prow + lane]) : 0;
#pragma unroll
    for (int o = 32; o > 0; o >>= 1) cp += __shfl_xor(cp, o);
    const int cnt = cp;
    float v[12];
#pragma unroll
    for (int w = 0; w < 3; w++) {
      float4 f4 = ((const float4*)row)[w * 64 + lane];
      v[w * 4 + 0] = f4.x; v[w * 4 + 1] = f4.y; v[w * 4 + 2] = f4.z; v[w * 4 + 3] = f4.w;
    }
    unsigned key[12];
    unsigned mnk = 0xFFFFFFFFu, mxk = 0u;
#pragma unroll
    for (int r = 0; r < 12; r++) {
      int bit = (int)((wd[r >> 2] >> (((lane & 15) << 2) + (r & 3))) & 1ULL);
      unsigned kf = f2key(v[r]);
      key[r] = bit ? kf : 0xFFFFFFFFu;   // masked-out -> sorts above all valid keys
      mnk = min(mnk, key[r]);
      mxk = max(mxk, bit ? kf : 0u);
    }
#pragma unroll
    for (int o = 32; o > 0; o >>= 1) {
      mnk = min(mnk, (unsigned)__shfl_xor((int)mnk, o));
      mxk = max(mxk, (unsigned)__shfl_xor((int)mxk, o));
    }
    float thr;
    if (cnt == 0) {
      thr = -INF;
    } else {
      float pos = 0.75f * (float)(cnt - 1);   // exact in f32
      int k0 = (int)pos;
      float f = pos - (float)k0;
      int target = k0 + 1;
      unsigned lo = mnk, hi = mxk;            // tight seed: valid-key min/max
      while (lo < hi) {                       // exact k0-th smallest
        unsigned mid = lo + ((hi - lo) >> 1);
        int c = 0;
#pragma unroll
        for (int r = 0; r < 12; r++) c += __builtin_popcountll(__ballot(key[r] <= mid));
        if (c >= target) hi = mid; else lo = mid + 1;
      }
      unsigned ka = lo;
      float a = key2f(ka);
      float b2;
      if (k0 + 1 >= cnt) {
        b2 = a;
      } else {
        int c1 = 0;
#pragma unroll
        for (int r = 0; r < 12; r++) c1 += __builtin_popcountll(__ballot(key[r] <= ka));
        if (c1 >= k0 + 2) {
          b2 = a;                             // duplicate covers rank k0+1
        } else {
          unsigned mn = 0xFFFFFFFFu;
#pragma unroll
          for (int r = 0; r < 12; r++) mn = min(mn, (key[r] > ka) ? key[r] : 0xFFFFFFFFu);
#pragma unroll
          for (int o = 32; o > 0; o >>= 1) mn = min(mn, (unsigned)__shfl_xor((int)mn, o));
          b2 = key2f(mn);
        }
      }
      thr = a + f * (b2 - a);
    }
    float* orow = out + OFF_TI + ((size_t)kk * NN + n) * MM;
#pragma unroll
    for (int w = 0; w < 3; w++) {
      unsigned long long ww = wd[w];
      int sh = (lane & 15) << 2;
      float4 o;
      o.x = (((ww >> (sh + 0)) & 1ULL) && v[w * 4 + 0] < thr) ? 1.f : 0.f;
      o.y = (((ww >> (sh + 1)) & 1ULL) && v[w * 4 + 1] < thr) ? 1.f : 0.f;
      o.z = (((ww >> (sh + 2)) & 1ULL) && v[w * 4 + 2] < thr) ? 1.f : 0.f;
      o.w = (((ww >> (sh + 3)) & 1ULL) && v[w * 4 + 3] < thr) ? 1.f : 0.f;
      ((float4*)orow)[w * 64 + lane] = o;
    }
  }
}

extern "C" void kernel_launch(void* const* d_in, const int* in_sizes, int n_in,
                              void* d_out, int out_size, void* d_ws, size_t ws_size,
                              hipStream_t stream) {
  (void)in_sizes; (void)n_in; (void)out_size; (void)ws_size;
  const float* qk  = (const float*)d_in[0];   // (1,768,64)
  const float* kks = (const float*)d_in[1];   // (1,8,768,64)
  const void*  qm  = d_in[2];                 // (8,768,768) bool/int
  const void*  km  = d_in[3];                 // (8,768,768) bool/int
  // perm1/perm2 unused: permutations make the solver sums iteration-invariant.
  float* out = (float*)d_out;
  float* wsf = (float*)d_ws;
  char*  wsb = (char*)d_ws;
  float* numpart = wsf + NUMP_OFF;
  float* model   = wsf + MODEL_OFF;
  float* xtb     = wsf + XT_OFF;
  float* errb    = wsf + ERR_OFF;
  float* esum = (float*)(wsb + ESUM_B);
  int*   ecnt = (int*)(wsb + ECNT_B);
  int*   denp = (int*)(wsb + DENP_B);
  unsigned long long* pmw = (unsigned long long*)(wsb + PM_B);

  k_solve<<<dim3(8, 8, BI), 256, 0, stream>>>(qk, kks, qm, km, numpart, denp, pmw);
  k_model<<<64, 256, 0, stream>>>(numpart, denp, model);
  k_xt<<<dim3(32, BI), 256, 0, stream>>>(qk, model, xtb);
  k_err<<<dim3(12, 12, BI), 256, 0, stream>>>(xtb, kks, pmw, errb, esum, ecnt);
  k_quant<<<512, 256, 0, stream>>>(errb, pmw, esum, ecnt, model, out);
}

// Round 10
// 177.108 us; speedup vs baseline: 1.0970x; 1.0970x over previous
//
#include <hip/hip_runtime.h>
#include <math.h>

// Problem constants (B=1, S=8, N=M=768, D=64, IT=16, RATIO=0.6, THR=0.75, K=8)
#define NN 768
#define MM 768
#define DD 64
#define BI 8            // B*S
#define RN 460          // int(0.6*768)
#define KTOP 8

// Output layout (concatenated flat: ti, tm, topk_err), all f32
static constexpr size_t OFF_TI = 0;                                  // (1,8,768,768)
static constexpr size_t OFF_TM = (size_t)KTOP * NN * MM;             // (1,8,64,64)
static constexpr size_t OFF_TE = OFF_TM + (size_t)KTOP * DD * DD;    // (1,8)

// Workspace layout. No zero-init: every location written before read.
static constexpr size_t TP_OFF    = 0;                                     // tpart (8c,8b,460,64)
static constexpr size_t NUMP_OFF  = TP_OFF + (size_t)8 * BI * RN * DD;     // numpart (8,8,64,64)
static constexpr size_t MODEL_OFF = NUMP_OFF + (size_t)8 * BI * DD * DD;   // model (8,64,64)
static constexpr size_t XT_OFF    = MODEL_OFF + (size_t)BI * DD * DD;      // xt (8,768,64)
static constexpr size_t ERR_OFF   = XT_OFF + (size_t)BI * NN * DD;         // err (8,768,768)
static constexpr size_t FEND      = ERR_OFF + (size_t)BI * NN * MM;
static constexpr size_t ESUM_B = FEND * 4;            // float[1152]
static constexpr size_t ECNT_B = ESUM_B + 1152 * 4;   // int[1152]
static constexpr size_t DENP_B = ECNT_B + 1152 * 4;   // int[512]
static constexpr size_t PM_B   = DENP_B + 512 * 4 + 32;  // u64[8*768*12] packed mask (8-aligned)

__device__ __forceinline__ unsigned f2key(float f) {
  unsigned u = __float_as_uint(f);
  return (u & 0x80000000u) ? ~u : (u | 0x80000000u);
}
__device__ __forceinline__ float key2f(unsigned k) {
  unsigned u = (k & 0x80000000u) ? (k ^ 0x80000000u) : ~k;
  return __uint_as_float(u);
}

// Kernel 0: pack qm&km into u64 words pm[(b*768+n)*12 + w] with ZERO serial chains:
// each thread does 6 independent vector loads (3 groups x {qm,km}), computes 4-bit
// nibbles, LDS-stages them; 48 threads assemble 16 nibbles -> one u64 word each.
// Block covers 4 mask rows (3072 elems); grid (192 row-groups, 8 b).
__global__ __launch_bounds__(256) void k_pack(
    const void* __restrict__ qm, const void* __restrict__ km,
    unsigned long long* __restrict__ pmw) {
  __shared__ __align__(16) unsigned char nib[768];
  __shared__ int flg[4];
  const int tid = threadIdx.x, lane = tid & 63, g = tid >> 6;
  // mask storage-layout detection (first 1 KB of qm, L2-hot): int32 0/1 data has
  // all-zero high bytes; bool-byte data has nonzero bytes at %4 != 0.
  {
    unsigned w0 = ((const unsigned*)qm)[tid];
    unsigned long long any = __ballot((w0 & 0xFFFFFF00u) != 0);
    if (lane == 0) flg[g] = (any != 0) ? 1 : 0;
  }
  __syncthreads();
  const int flag = (flg[0] | flg[1] | flg[2] | flg[3]) ? 0 : 1;   // 1 => int32 layout
  const int rg = blockIdx.x, b = blockIdx.y;
  const size_t E0 = ((size_t)b * NN + (size_t)rg * 4) * MM;       // first elem of 4-row chunk
  unsigned nb[3];
#pragma unroll
  for (int k = 0; k < 3; k++) {
    int gi = tid + 256 * k;                 // elem group [4gi, 4gi+4) of chunk
    size_t e = E0 + 4 * (size_t)gi;
    unsigned nibble;
    if (flag) {
      uint4 qa = *(const uint4*)((const int*)qm + e);
      uint4 ka = *(const uint4*)((const int*)km + e);
      nibble = ((qa.x && ka.x) ? 1u : 0u) | ((qa.y && ka.y) ? 2u : 0u) |
               ((qa.z && ka.z) ? 4u : 0u) | ((qa.w && ka.w) ? 8u : 0u);
    } else {
      unsigned qa = *(const unsigned*)((const unsigned char*)qm + e);
      unsigned ka = *(const unsigned*)((const unsigned char*)km + e);
      nibble = (((qa & 0xFFu) && (ka & 0xFFu)) ? 1u : 0u) |
               (((qa & 0xFF00u) && (ka & 0xFF00u)) ? 2u : 0u) |
               (((qa & 0xFF0000u) && (ka & 0xFF0000u)) ? 4u : 0u) |
               (((qa & 0xFF000000u) && (ka & 0xFF000000u)) ? 8u : 0u);
    }
    nb[k] = nibble;
  }
#pragma unroll
  for (int k = 0; k < 3; k++) nib[tid + 256 * k] = (unsigned char)nb[k];
  __syncthreads();
  if (tid < 48) {                           // 4 rows x 12 words
    uint4 q4 = *(const uint4*)&nib[tid * 16];
    unsigned long long w = 0;
    unsigned dw[4] = {q4.x, q4.y, q4.z, q4.w};
#pragma unroll
    for (int q = 0; q < 4; q++) {
      w |= (unsigned long long)(dw[q] & 0xFu) << (16 * q + 0);
      w |= (unsigned long long)((dw[q] >> 8) & 0xFu) << (16 * q + 4);
      w |= (unsigned long long)((dw[q] >> 16) & 0xFu) << (16 * q + 8);
      w |= (unsigned long long)((dw[q] >> 24) & 0xFu) << (16 * q + 12);
    }
    int n = rg * 4 + tid / 12, ww = tid % 12;
    pmw[((size_t)b * NN + n) * 12 + ww] = w;
  }
}

// Kernel 1: dense masked GEMM from packed bits: tpart[c,b,n,e] = sum_{m in word c}
// bit * y[b,m,e]. Bit-select = shift/and/add (3 VALU per MAC), 16 independent accs.
// grid (ntile 0..7, c 0..7, b 0..7).
__global__ __launch_bounds__(256) void k_tgemm(
    const float* __restrict__ kks, const unsigned long long* __restrict__ pmw,
    float* __restrict__ tpart, int* __restrict__ denp) {
  __shared__ float ys[64 * 68];
  __shared__ int cntsh[4];
  const int tid = threadIdx.x, lane = tid & 63, g = tid >> 6;
  const int ntile = blockIdx.x, c = blockIdx.y, b = blockIdx.z;
  const int m0 = c * 64;
  const float* yb = kks + (size_t)b * MM * DD;
  for (int q = tid; q < 1024; q += 256) {
    int r = q >> 4, col = (q & 15) * 4;
    *(float4*)&ys[r * 68 + col] = *(const float4*)&yb[(size_t)(m0 + r) * DD + col];
  }
  const int n0 = ntile * 64 + g * 16;
  unsigned wlo[16], whi[16];
  int cnt = 0;
#pragma unroll
  for (int i = 0; i < 16; i++) {
    int n = n0 + i;
    unsigned long long w = pmw[((size_t)b * NN + n) * 12 + c];
    if (c == 7) w &= 0xFFFULL;           // solver samples m < 460 (448 + 12)
    wlo[i] = (unsigned)w; whi[i] = (unsigned)(w >> 32);
    if (n < RN) cnt += __builtin_popcountll(w);
  }
  __syncthreads();
  float acc[16];
#pragma unroll
  for (int i = 0; i < 16; i++) acc[i] = 0.f;
#pragma unroll 4
  for (int m = 0; m < 32; m++) {
    int yi = __float_as_int(ys[m * 68 + lane]);
#pragma unroll
    for (int i = 0; i < 16; i++) {
      int sel = ((int)(wlo[i] << (31 - m))) >> 31;
      acc[i] += __int_as_float(yi & sel);
    }
  }
#pragma unroll 4
  for (int m = 0; m < 32; m++) {
    int yi = __float_as_int(ys[(m + 32) * 68 + lane]);
#pragma unroll
    for (int i = 0; i < 16; i++) {
      int sel = ((int)(whi[i] << (31 - m))) >> 31;
      acc[i] += __int_as_float(yi & sel);
    }
  }
#pragma unroll
  for (int i = 0; i < 16; i++) {
    int n = n0 + i;
    if (n < RN)
      tpart[(((size_t)c * BI + b) * RN + n) * DD + lane] = acc[i];
  }
  if (lane == 0) cntsh[g] = cnt;         // cnt uniform across lanes
  __syncthreads();
  if (tid == 0) denp[(b * 8 + c) * 8 + ntile] = cntsh[0] + cntsh[1] + cntsh[2] + cntsh[3];
}

// Kernel 2: numpart[chunk,b,d,e] = sum_{n in 64-row chunk} x[n,d]*t[b,n,e]
// (8 chunks of 64 rows; t = sum of the 8 c-split tpart copies)
__global__ __launch_bounds__(256) void k_num(
    const float* __restrict__ qk, const float* __restrict__ tpart, float* __restrict__ numpart) {
  __shared__ float xs[16 * 64];
  __shared__ float ts[16 * 64];
  const int tid = threadIdx.x, lane = tid & 63, g = tid >> 6;
  const int chunk = blockIdx.x, b = blockIdx.y;
  float acc[16];
#pragma unroll
  for (int i = 0; i < 16; i++) acc[i] = 0.f;
  for (int it = 0; it < 4; it++) {
    int base = chunk * 64 + it * 16;
    for (int l = tid; l < 1024; l += 256) {
      int r = l >> 6, col = l & 63;
      int n = base + r;
      float xv = 0.f, tv = 0.f;
      if (n < RN) {
        xv = qk[(size_t)n * DD + col];
#pragma unroll
        for (int cc = 0; cc < 8; cc++)
          tv += tpart[(((size_t)cc * BI + b) * RN + n) * DD + col];
      }
      xs[l] = xv; ts[l] = tv;
    }
    __syncthreads();
#pragma unroll 4
    for (int r = 0; r < 16; r++) {
      float tv = ts[r * 64 + lane];
#pragma unroll
      for (int i = 0; i < 16; i++) acc[i] += xs[r * 64 + g + i * 4] * tv;
    }
    __syncthreads();
  }
#pragma unroll
  for (int i = 0; i < 16; i++)
    numpart[((size_t)chunk * BI + b) * (DD * DD) + (size_t)(g + i * 4) * DD + lane] = acc[i];
}

// Kernel 3: model[b] = (sum_chunk numpart) / (den[b] + 1e-6)
__global__ __launch_bounds__(256) void k_model(
    const float* __restrict__ numpart, const int* __restrict__ denp, float* __restrict__ model) {
  __shared__ float invp;
  const int tid = threadIdx.x;
  const int b = blockIdx.x >> 3, part = blockIdx.x & 7;
  if (tid < 64) {
    int v = denp[b * 64 + tid];
#pragma unroll
    for (int o = 32; o > 0; o >>= 1) v += __shfl_xor(v, o);
    if (tid == 0) invp = 1.f / ((float)v + 1e-6f);
  }
  __syncthreads();
  float inv = invp;
  for (int l = part * 512 + tid; l < part * 512 + 512; l += 256) {
    float s = 0.f;
#pragma unroll
    for (int cc = 0; cc < 8; cc++) s += numpart[((size_t)cc * BI + b) * (DD * DD) + l];
    model[(size_t)b * (DD * DD) + l] = s * inv;
  }
}

// Kernel 4: xt[b,n,e] = sum_d x[n,d]*model[b,d,e]  (24 rows per block)
__global__ __launch_bounds__(256) void k_xt(
    const float* __restrict__ qk, const float* __restrict__ model, float* __restrict__ xt) {
  __shared__ float ml[DD * DD];
  const int tid = threadIdx.x, lane = tid & 63, g = tid >> 6;
  const int seg = blockIdx.x, b = blockIdx.y;
  const float4* msrc = (const float4*)(model + (size_t)b * DD * DD);
  for (int q = tid; q < 1024; q += 256) ((float4*)ml)[q] = msrc[q];
  __syncthreads();
#pragma unroll
  for (int rr = 0; rr < 6; rr++) {
    int n = seg * 24 + g * 6 + rr;
    float acc = 0.f;
#pragma unroll 8
    for (int d = 0; d < DD; d++) acc += qk[(size_t)n * DD + d] * ml[d * DD + lane];
    xt[((size_t)b * NN + n) * DD + lane] = acc;
  }
}

// Kernel 5: err[b,i,j] = ||xt_i||^2 + ||y_j||^2 - 2 xt_i.y_j, stored ONLY where mask
// bit set (quant gets validity from pm, so no INF sentinel writes).
__global__ __launch_bounds__(256) void k_err(
    const float* __restrict__ xt, const float* __restrict__ kks,
    const unsigned long long* __restrict__ pmw,
    float* __restrict__ err, float* __restrict__ esum, int* __restrict__ ecnt) {
  __shared__ float As[64 * 68];
  __shared__ float Bs[64 * 68];
  __shared__ float xx[64], yy[64];
  __shared__ float rsum[256];
  __shared__ int rcnt[256];
  const int b = blockIdx.z, wj = blockIdx.x;
  const int i0 = blockIdx.y * 64, j0 = wj * 64;
  const int tid = threadIdx.x, tx = tid & 15, ty = tid >> 4;
  const float* xb = xt + ((size_t)b * NN + i0) * DD;
  const float* yb = kks + ((size_t)b * MM + j0) * DD;
  for (int q = tid; q < 1024; q += 256) {
    int r = q >> 4, c = q & 15;
    *(float4*)&As[r * 68 + c * 4] = ((const float4*)(xb + (size_t)r * DD))[c];
    *(float4*)&Bs[r * 68 + c * 4] = ((const float4*)(yb + (size_t)r * DD))[c];
  }
  __syncthreads();
  if (tid < 64) {
    float s = 0.f;
#pragma unroll 8
    for (int k2 = 0; k2 < 64; k2++) { float v = As[tid * 68 + k2]; s += v * v; }
    xx[tid] = s;
  } else if (tid < 128) {
    int r = tid - 64;
    float s = 0.f;
#pragma unroll 8
    for (int k2 = 0; k2 < 64; k2++) { float v = Bs[r * 68 + k2]; s += v * v; }
    yy[r] = s;
  }
  __syncthreads();
  float acc[4][4];
#pragma unroll
  for (int ii = 0; ii < 4; ii++)
#pragma unroll
    for (int jj = 0; jj < 4; jj++) acc[ii][jj] = 0.f;
  for (int k2 = 0; k2 < 64; k2 += 4) {
    float4 av[4], bv[4];
#pragma unroll
    for (int ii = 0; ii < 4; ii++) av[ii] = *(const float4*)&As[(ty + 16 * ii) * 68 + k2];
#pragma unroll
    for (int jj = 0; jj < 4; jj++) bv[jj] = *(const float4*)&Bs[(tx + 16 * jj) * 68 + k2];
#pragma unroll
    for (int ii = 0; ii < 4; ii++)
#pragma unroll
      for (int jj = 0; jj < 4; jj++)
        acc[ii][jj] += av[ii].x * bv[jj].x + av[ii].y * bv[jj].y +
                       av[ii].z * bv[jj].z + av[ii].w * bv[jj].w;
  }
  float psum = 0.f;
  int pcnt = 0;
#pragma unroll
  for (int ii = 0; ii < 4; ii++) {
    int i = i0 + ty + 16 * ii;
    unsigned long long word = pmw[((size_t)b * NN + i) * 12 + wj];
    size_t rowb = ((size_t)b * NN + i) * MM;
#pragma unroll
    for (int jj = 0; jj < 4; jj++) {
      int j = j0 + tx + 16 * jj;
      int cm = (int)((word >> (tx + 16 * jj)) & 1ULL);
      float v = xx[ty + 16 * ii] + yy[tx + 16 * jj] - 2.f * acc[ii][jj];
      if (cm) { err[rowb + j] = v; psum += v; pcnt++; }
    }
  }
  rsum[tid] = psum;
  rcnt[tid] = pcnt;
  __syncthreads();
  for (int s = 128; s > 0; s >>= 1) {
    if (tid < s) { rsum[tid] += rsum[tid + s]; rcnt[tid] += rcnt[tid + s]; }
    __syncthreads();
  }
  if (tid == 0) {
    int t = b * 144 + blockIdx.y * 12 + wj;
    esum[t] = rsum[0];
    ecnt[t] = rcnt[0];
  }
}

// Kernel 6 (quant + rank fused): every block reduces the esum/ecnt partials (cheap,
// parallel), computes the descending order (== lax.top_k, K=S); block 0 writes TE+TM.
// Then per-row 0.75 nanquantile via ballot binary search (validity from pm bits).
// One row per WAVE, grid 1536 (4 waves/block) for max latency hiding.
__global__ __launch_bounds__(256) void k_quant(
    const float* __restrict__ err, const unsigned long long* __restrict__ pmw,
    const float* __restrict__ esum, const int* __restrict__ ecnt,
    const float* __restrict__ model, float* __restrict__ out) {
  __shared__ float avg_sh[BI];
  __shared__ int ords_sh[BI];
  const int bid = blockIdx.x, tid = threadIdx.x, lane = tid & 63, g = tid >> 6;
  const float INF = __builtin_inff();
  for (int h = 0; h < 2; h++) {
    int b = g * 2 + h, base = b * 144;
    float s = esum[base + lane] + esum[base + 64 + lane] + ((lane < 16) ? esum[base + 128 + lane] : 0.f);
    int ct = ecnt[base + lane] + ecnt[base + 64 + lane] + ((lane < 16) ? ecnt[base + 128 + lane] : 0);
#pragma unroll
    for (int o = 32; o > 0; o >>= 1) { s += __shfl_xor(s, o); ct += __shfl_xor(ct, o); }
    if (lane == 0) avg_sh[b] = s / (float)ct;
  }
  __syncthreads();
  if (tid == 0) {
    unsigned used = 0;
#pragma unroll
    for (int k = 0; k < KTOP; k++) {
      int best = 0;
      float bv = -INF;
#pragma unroll
      for (int b = 0; b < BI; b++)
        if (!((used >> b) & 1u) && avg_sh[b] > bv) { bv = avg_sh[b]; best = b; }
      used |= 1u << best;
      ords_sh[k] = best;
    }
  }
  __syncthreads();
  if (bid == 0) {
    if (tid < KTOP) out[OFF_TE + tid] = avg_sh[ords_sh[tid]];
    for (int l = tid; l < KTOP * DD * DD; l += 256) {
      int k = l >> 12;
      out[OFF_TM + l] = model[(size_t)ords_sh[k] * (DD * DD) + (l & (DD * DD - 1))];
    }
  }
  const int kk = bid / 192, seg = bid % 192;   // 192 blocks per k, 4 rows each (1/wave)
  const int b = ords_sh[kk];
  const int n = seg * 4 + g;
  const float* row = err + ((size_t)b * NN + n) * MM;
  size_t prow = ((size_t)b * NN + n) * 12;
  unsigned long long wd[3];
#pragma unroll
  for (int w = 0; w < 3; w++) wd[w] = pmw[prow + w * 4 + (lane >> 4)];
  int cp = (lane < 12) ? __builtin_popcountll(pmw[prow + lane]) : 0;
#pragma unroll
  for (int o = 32; o > 0; o >>= 1) cp += __shfl_xor(cp, o);
  const int cnt = cp;
  float v[12];
#pragma unroll
  for (int w = 0; w < 3; w++) {
    float4 f4 = ((const float4*)row)[w * 64 + lane];
    v[w * 4 + 0] = f4.x; v[w * 4 + 1] = f4.y; v[w * 4 + 2] = f4.z; v[w * 4 + 3] = f4.w;
  }
  unsigned key[12];
  unsigned mnk = 0xFFFFFFFFu, mxk = 0u;
#pragma unroll
  for (int r = 0; r < 12; r++) {
    int bit = (int)((wd[r >> 2] >> (((lane & 15) << 2) + (r & 3))) & 1ULL);
    unsigned kf = f2key(v[r]);
    key[r] = bit ? kf : 0xFFFFFFFFu;   // masked-out -> sorts above all valid keys
    mnk = min(mnk, key[r]);
    mxk = max(mxk, bit ? kf : 0u);
  }
#pragma unroll
  for (int o = 32; o > 0; o >>= 1) {
    mnk = min(mnk, (unsigned)__shfl_xor((int)mnk, o));
    mxk = max(mxk, (unsigned)__shfl_xor((int)mxk, o));
  }
  float thr;
  if (cnt == 0) {
    thr = -INF;
  } else {
    float pos = 0.75f * (float)(cnt - 1);   // exact in f32
    int k0 = (int)pos;
    float f = pos - (float)k0;
    int target = k0 + 1;
    unsigned lo = mnk, hi = mxk;            // tight seed: valid-key min/max
    while (lo < hi) {                       // exact k0-th smallest
      unsigned mid = lo + ((hi - lo) >> 1);
      int c = 0;
#pragma unroll
      for (int r = 0; r < 12; r++) c += __builtin_popcountll(__ballot(key[r] <= mid));
      if (c >= target) hi = mid; else lo = mid + 1;
    }
    unsigned ka = lo;
    float a = key2f(ka);
    float b2;
    if (k0 + 1 >= cnt) {
      b2 = a;
    } else {
      int c1 = 0;
#pragma unroll
      for (int r = 0; r < 12; r++) c1 += __builtin_popcountll(__ballot(key[r] <= ka));
      if (c1 >= k0 + 2) {
        b2 = a;                             // duplicate covers rank k0+1
      } else {
        unsigned mn = 0xFFFFFFFFu;
#pragma unroll
        for (int r = 0; r < 12; r++) mn = min(mn, (key[r] > ka) ? key[r] : 0xFFFFFFFFu);
#pragma unroll
        for (int o = 32; o > 0; o >>= 1) mn = min(mn, (unsigned)__shfl_xor((int)mn, o));
        b2 = key2f(mn);
      }
    }
    thr = a + f * (b2 - a);
  }
  float* orow = out + OFF_TI + ((size_t)kk * NN + n) * MM;
#pragma unroll
  for (int w = 0; w < 3; w++) {
    unsigned long long ww = wd[w];
    int sh = (lane & 15) << 2;
    float4 o;
    o.x = (((ww >> (sh + 0)) & 1ULL) && v[w * 4 + 0] < thr) ? 1.f : 0.f;
    o.y = (((ww >> (sh + 1)) & 1ULL) && v[w * 4 + 1] < thr) ? 1.f : 0.f;
    o.z = (((ww >> (sh + 2)) & 1ULL) && v[w * 4 + 2] < thr) ? 1.f : 0.f;
    o.w = (((ww >> (sh + 3)) & 1ULL) && v[w * 4 + 3] < thr) ? 1.f : 0.f;
    ((float4*)orow)[w * 64 + lane] = o;
  }
}

extern "C" void kernel_launch(void* const* d_in, const int* in_sizes, int n_in,
                              void* d_out, int out_size, void* d_ws, size_t ws_size,
                              hipStream_t stream) {
  (void)in_sizes; (void)n_in; (void)out_size; (void)ws_size;
  const float* qk  = (const float*)d_in[0];   // (1,768,64)
  const float* kks = (const float*)d_in[1];   // (1,8,768,64)
  const void*  qm  = d_in[2];                 // (8,768,768) bool/int
  const void*  km  = d_in[3];                 // (8,768,768) bool/int
  // perm1/perm2 unused: permutations make the solver sums iteration-invariant.
  float* out = (float*)d_out;
  float* wsf = (float*)d_ws;
  char*  wsb = (char*)d_ws;
  float* tpart   = wsf + TP_OFF;
  float* numpart = wsf + NUMP_OFF;
  float* model   = wsf + MODEL_OFF;
  float* xtb     = wsf + XT_OFF;
  float* errb    = wsf + ERR_OFF;
  float* esum = (float*)(wsb + ESUM_B);
  int*   ecnt = (int*)(wsb + ECNT_B);
  int*   denp = (int*)(wsb + DENP_B);
  unsigned long long* pmw = (unsigned long long*)(wsb + PM_B);

  k_pack<<<dim3(192, BI), 256, 0, stream>>>(qm, km, pmw);
  k_tgemm<<<dim3(8, 8, BI), 256, 0, stream>>>(kks, pmw, tpart, denp);
  k_num<<<dim3(8, BI), 256, 0, stream>>>(qk, tpart, numpart);
  k_model<<<64, 256, 0, stream>>>(numpart, denp, model);
  k_xt<<<dim3(32, BI), 256, 0, stream>>>(qk, model, xtb);
  k_err<<<dim3(12, 12, BI), 256, 0, stream>>>(xtb, kks, pmw, errb, esum, ecnt);
  k_quant<<<1536, 256, 0, stream>>>(errb, pmw, esum, ecnt, model, out);
}